// Round 1
// baseline (741.638 us; speedup 1.0000x reference)
//
#include <hip/hip_runtime.h>
#include <hip/hip_bf16.h>

#define SEQ   512
#define BATCH 1024
#define HD    64
#define NG    256   // 4*H
#define NS    2     // samples per block

// One thread per gate row (256 threads). Weight row (W_ih[g] || W_hh[g]) lives
// in 128 VGPRs per thread. z = [x_t || h_{t-1}] per sample is broadcast from
// LDS (all lanes read same address -> conflict-free). c-state lives in a
// register of threads 0..127 (thread -> (sample, hidden unit)).
__global__ __launch_bounds__(256, 2)
void lstm_fused(const float* __restrict__ x,
                const float* __restrict__ W_ih,
                const float* __restrict__ W_hh,
                const float* __restrict__ b_ih,
                const float* __restrict__ b_hh,
                float* __restrict__ out)
{
    const int tid   = threadIdx.x;
    const int g     = tid;                 // gate row 0..255
    const int sBase = blockIdx.x * NS;

    __shared__ float zbuf[NS][128];        // [ x_t (64) | h (64) ] per sample
    __shared__ float pre[NS][NG];          // gate pre-activations

    // Load this thread's weight row into registers (one-time; L2-cached).
    float4 wih[16], whh[16];
    const float4* wi = (const float4*)(W_ih + g * HD);
    const float4* wh = (const float4*)(W_hh + g * HD);
    #pragma unroll
    for (int k = 0; k < 16; ++k) { wih[k] = wi[k]; whh[k] = wh[k]; }
    const float bias = b_ih[g] + b_hh[g];

    // Init: zbuf x-part = x[0], h-part = 0.
    if (tid < NS * HD) {
        const int s = tid >> 6, k = tid & 63;
        zbuf[s][k]      = x[(size_t)(sBase + s) * HD + k];
        zbuf[s][64 + k] = 0.f;
    }
    float c = 0.f;   // c-state of (s = tid>>6, j = tid&63) for tid < 128
    __syncthreads();

    for (int t = 0; t < SEQ; ++t) {
        // ---- gate matvec: pre[s][g] = bias + W_ih[g].x_t[s] + W_hh[g].h[s]
        float acc0 = bias, acc1 = bias;
        #pragma unroll
        for (int k = 0; k < 16; ++k) {
            const float4 w  = wih[k];
            const float4 z0 = *(const float4*)&zbuf[0][k * 4];
            const float4 z1 = *(const float4*)&zbuf[1][k * 4];
            acc0 = fmaf(w.x, z0.x, acc0); acc0 = fmaf(w.y, z0.y, acc0);
            acc0 = fmaf(w.z, z0.z, acc0); acc0 = fmaf(w.w, z0.w, acc0);
            acc1 = fmaf(w.x, z1.x, acc1); acc1 = fmaf(w.y, z1.y, acc1);
            acc1 = fmaf(w.z, z1.z, acc1); acc1 = fmaf(w.w, z1.w, acc1);
        }
        #pragma unroll
        for (int k = 0; k < 16; ++k) {
            const float4 w  = whh[k];
            const float4 z0 = *(const float4*)&zbuf[0][64 + k * 4];
            const float4 z1 = *(const float4*)&zbuf[1][64 + k * 4];
            acc0 = fmaf(w.x, z0.x, acc0); acc0 = fmaf(w.y, z0.y, acc0);
            acc0 = fmaf(w.z, z0.z, acc0); acc0 = fmaf(w.w, z0.w, acc0);
            acc1 = fmaf(w.x, z1.x, acc1); acc1 = fmaf(w.y, z1.y, acc1);
            acc1 = fmaf(w.z, z1.z, acc1); acc1 = fmaf(w.w, z1.w, acc1);
        }
        pre[0][g] = acc0;
        pre[1][g] = acc1;

        // ---- prefetch next x into regs (latency hidden under sync+elemwise)
        float xr = 0.f;
        if (tid < NS * HD && t + 1 < SEQ) {
            const int s = tid >> 6, k = tid & 63;
            xr = x[((size_t)(t + 1) * BATCH + sBase + s) * HD + k];
        }
        __syncthreads();   // pre[] visible; all zbuf reads of step t done

        // ---- elementwise LSTM cell (threads 0..127: one (sample, unit) each)
        if (tid < NS * HD) {
            const int s = tid >> 6, j = tid & 63;
            const float ig = pre[s][j];
            const float fg = pre[s][64 + j];
            const float gg = pre[s][128 + j];
            const float og = pre[s][192 + j];
            const float iv = 1.f / (1.f + __expf(-ig));
            const float fv = 1.f / (1.f + __expf(-fg));
            const float gv = 1.f - 2.f / (__expf(2.f * gg) + 1.f);   // tanh
            const float ov = 1.f / (1.f + __expf(-og));
            c = fv * c + iv * gv;
            const float th = 1.f - 2.f / (__expf(2.f * c) + 1.f);    // tanh
            const float h  = ov * th;
            out[((size_t)t * BATCH + sBase + s) * HD + j] = h;
            zbuf[s][64 + j] = h;    // h for next step
            zbuf[s][j]      = xr;   // x_{t+1}
        }
        __syncthreads();   // zbuf ready for next step
    }
}

extern "C" void kernel_launch(void* const* d_in, const int* in_sizes, int n_in,
                              void* d_out, int out_size, void* d_ws, size_t ws_size,
                              hipStream_t stream) {
    const float* x    = (const float*)d_in[0];
    const float* W_ih = (const float*)d_in[1];
    const float* W_hh = (const float*)d_in[2];
    const float* b_ih = (const float*)d_in[3];
    const float* b_hh = (const float*)d_in[4];
    float* out = (float*)d_out;

    lstm_fused<<<BATCH / NS, 256, 0, stream>>>(x, W_ih, W_hh, b_ih, b_hh, out);
}

// Round 3
// 339.074 us; speedup vs baseline: 2.1872x; 2.1872x over previous
//
#include <hip/hip_runtime.h>
#include <hip/hip_bf16.h>

#define SEQ   512
#define BATCH 1024
#define HD    64
#define NS    4                      // samples per block -> 256 blocks

typedef __attribute__((ext_vector_type(8))) short bf16x8;   // 8 bf16 = 4 VGPR
typedef __attribute__((ext_vector_type(4))) float f32x4;    // MFMA acc

// float -> bf16 raw bits, round-to-nearest-even
__device__ __forceinline__ unsigned short f2bf(float f) {
    unsigned u = __float_as_uint(f);
    return (unsigned short)((u + 0x7FFFu + ((u >> 16) & 1u)) >> 16);
}

// Persistent LSTM: one block = 4 batch samples for all 512 steps.
// Wave w owns hidden units [16w, 16w+16): its N-tiles are {w, 4+w, 8+w, 12+w}
// (= the i, f, g, o slices for those units), so the cell update needs no
// cross-wave exchange; only h is shared via LDS for the next step's A operand.
__global__ __launch_bounds__(256, 1)
void lstm_mfma(const float* __restrict__ x,
               const float* __restrict__ W_ih,
               const float* __restrict__ W_hh,
               const float* __restrict__ b_ih,
               const float* __restrict__ b_hh,
               float* __restrict__ out)
{
    __shared__ unsigned short Wbf[256 * 128];  // 64 KB: [gate n][k]  (k<64: W_ih, k>=64: W_hh)
    __shared__ unsigned short zb[16 * 128];    // 4 KB swizzled: row=sample(16), col=[x(64)|h(64)]

    const int tid  = threadIdx.x;
    const int w    = tid >> 6;       // wave 0..3
    const int ln   = tid & 63;
    const int col  = ln & 15;        // tile column (N)  / redistributed unit
    const int kg   = ln >> 4;        // k-group for A/B fragments
    const int sBase = blockIdx.x * NS;

    // ---- one-time: bf16 weights into LDS (coalesced), zero z-buffer ----
    for (int idx = tid; idx < 256 * 64; idx += 256) {
        const int n = idx >> 6, k = idx & 63;
        Wbf[n * 128 + k]      = f2bf(W_ih[idx]);
        Wbf[n * 128 + 64 + k] = f2bf(W_hh[idx]);
    }
    for (int idx = tid; idx < 16 * 128; idx += 256) zb[idx] = 0;
    __syncthreads();

    // ---- B fragments (weights) -> registers for the whole sequence ----
    // B[k][n] = W[n][k]; lane holds 8 consecutive k of gate n = ntile*16+col.
    bf16x8 bfr[4][4];                // [gate i/f/g/o][k-tile]
    #pragma unroll
    for (int g4 = 0; g4 < 4; ++g4) {
        #pragma unroll
        for (int kt = 0; kt < 4; ++kt) {
            const int n = (g4 * 4 + w) * 16 + col;
            const int k = kt * 32 + kg * 8;
            bfr[g4][kt] = *(const bf16x8*)&Wbf[n * 128 + k];
        }
    }
    // bias per output column (gate g4*64 + w*16 + col); folded into acc init
    float bias[4];
    #pragma unroll
    for (int g4 = 0; g4 < 4; ++g4) {
        const int gg = g4 * 64 + w * 16 + col;
        bias[g4] = b_ih[gg] + b_hh[gg];
    }
    // x[0] into zb (rows 0-3, cols 0-63); h-half stays 0
    {
        const int s2 = tid >> 6, k2 = tid & 63;
        const unsigned short v = f2bf(x[(size_t)(sBase + s2) * HD + k2]);
        *(unsigned short*)((char*)zb + s2 * 256 + ((2 * k2) ^ ((s2 & 7) << 4))) = v;
    }
    __syncthreads();

    const int s = ln >> 4;           // redistributed sample index (0..3)
    float c_st = 0.f;                // cell state of (sample s, unit w*16+col)

    // loop-invariant addresses
    const float* xp = x + ((size_t)BATCH + sBase + (tid >> 6)) * HD + (tid & 63); // x[t+1]
    float* outp = out + (size_t)(sBase + s) * HD + w * 16 + col;
    const char* arp[4];
    #pragma unroll
    for (int kt = 0; kt < 4; ++kt) {
        const int row = ln & 15;
        arp[kt] = (const char*)zb + row * 256 + ((kt * 64 + kg * 16) ^ ((row & 7) << 4));
    }
    char* hwp = (char*)zb + s * 256 + ((2 * (64 + w * 16 + col)) ^ ((s & 7) << 4));
    char* xwp = (char*)zb + (tid >> 6) * 256 + ((2 * (tid & 63)) ^ (((tid >> 6) & 7) << 4));

    for (int t = 0; t < SEQ; ++t) {
        // A fragments: rows=samples (4 valid, rest zero), 8 k each, swizzled LDS
        bf16x8 a[4];
        #pragma unroll
        for (int kt = 0; kt < 4; ++kt) a[kt] = *(const bf16x8*)arp[kt];

        // prefetch x[t+1] under the MFMAs
        float xr = 0.f;
        if (t + 1 < SEQ) xr = xp[(size_t)t * BATCH * HD];

        f32x4 acc[4];
        #pragma unroll
        for (int g4 = 0; g4 < 4; ++g4) {
            const float b = bias[g4];
            acc[g4][0] = b; acc[g4][1] = b; acc[g4][2] = b; acc[g4][3] = b;
        }
        #pragma unroll
        for (int g4 = 0; g4 < 4; ++g4) {
            #pragma unroll
            for (int kt = 0; kt < 4; ++kt)
                acc[g4] = __builtin_amdgcn_mfma_f32_16x16x32_bf16(a[kt], bfr[g4][kt], acc[g4], 0, 0, 0);
        }

        __syncthreads();   // all zb reads of step t complete

        // redistribute: D[r][col] lives in lane col, reg r (r=sample).
        // move to lane 16*r+col so all 64 lanes do one cell update.
        float gv[4];
        #pragma unroll
        for (int g4 = 0; g4 < 4; ++g4) {
            const float v0 = __shfl(acc[g4][0], col);
            const float v1 = __shfl(acc[g4][1], col);
            const float v2 = __shfl(acc[g4][2], col);
            const float v3 = __shfl(acc[g4][3], col);
            const float t01 = (s & 1) ? v1 : v0;
            const float t23 = (s & 1) ? v3 : v2;
            gv[g4] = (s & 2) ? t23 : t01;
        }

        const float iv = 1.f / (1.f + __expf(-gv[0]));
        const float fv = 1.f / (1.f + __expf(-gv[1]));
        const float gg = 1.f - 2.f / (__expf(2.f * gv[2]) + 1.f);   // tanh
        const float ov = 1.f / (1.f + __expf(-gv[3]));
        c_st = fv * c_st + iv * gg;
        const float th = 1.f - 2.f / (__expf(2.f * c_st) + 1.f);    // tanh
        const float h  = ov * th;

        outp[(size_t)t * BATCH * HD] = h;

        // h (bf16) and x[t+1] (bf16) into zb for the next step
        *(unsigned short*)hwp = f2bf(h);
        if (t + 1 < SEQ) *(unsigned short*)xwp = f2bf(xr);
        __syncthreads();   // zb ready for step t+1
    }
}

extern "C" void kernel_launch(void* const* d_in, const int* in_sizes, int n_in,
                              void* d_out, int out_size, void* d_ws, size_t ws_size,
                              hipStream_t stream) {
    const float* x    = (const float*)d_in[0];
    const float* W_ih = (const float*)d_in[1];
    const float* W_hh = (const float*)d_in[2];
    const float* b_ih = (const float*)d_in[3];
    const float* b_hh = (const float*)d_in[4];
    float* out = (float*)d_out;

    lstm_mfma<<<BATCH / NS, 256, 0, stream>>>(x, W_ih, W_hh, b_ih, b_hh, out);
}